// Round 1
// baseline (2019.298 us; speedup 1.0000x reference)
//
#include <hip/hip_runtime.h>
#include <math.h>

#define N_SAMPLES 200
#define FEAT 64
#define GRIDN 128

__device__ __forceinline__ float trilinear(const float* __restrict__ g,
                                           float x, float y, float z) {
    const float W = 128.f, H = 128.f, D = 128.f;
    float gx = ((x + 1.f) * W - 1.f) * 0.5f;
    float gy = ((y + 1.f) * H - 1.f) * 0.5f;
    float gz = ((z + 1.f) * D - 1.f) * 0.5f;
    float x0 = floorf(gx), y0 = floorf(gy), z0 = floorf(gz);
    float out = 0.f;
#pragma unroll
    for (int dz = 0; dz < 2; ++dz)
#pragma unroll
        for (int dy = 0; dy < 2; ++dy)
#pragma unroll
            for (int dx = 0; dx < 2; ++dx) {
                float xi = x0 + dx, yi = y0 + dy, zi = z0 + dz;
                float w = (1.f - fabsf(gx - xi)) * (1.f - fabsf(gy - yi)) *
                          (1.f - fabsf(gz - zi));
                bool valid = (xi >= 0.f) && (xi < W) && (yi >= 0.f) &&
                             (yi < H) && (zi >= 0.f) && (zi < D);
                int xc = (int)fminf(fmaxf(xi, 0.f), 127.f);
                int yc = (int)fminf(fmaxf(yi, 0.f), 127.f);
                int zc = (int)fminf(fmaxf(zi, 0.f), 127.f);
                float v = valid ? g[(zc * GRIDN + yc) * GRIDN + xc] : 0.f;
                out += w * v;
            }
    return out;
}

__global__ __launch_bounds__(64) void nerf_kernel(
    const float* __restrict__ rays_o, const float* __restrict__ rays_d,
    const float* __restrict__ grid, const float* __restrict__ aabb,
    const float* __restrict__ fw1, const float* __restrict__ fb1,
    const float* __restrict__ fw2, const float* __restrict__ fb2,
    const float* __restrict__ sw, const float* __restrict__ sb,
    const float* __restrict__ rw1, const float* __restrict__ rb1,
    const float* __restrict__ rw2, const float* __restrict__ rb2,
    float* __restrict__ out) {
    const int ray = blockIdx.x;
    const int f = threadIdx.x;  // 0..63

    __shared__ float s_h[FEAT];
    __shared__ float s_feat[FEAT];

    const float ox = rays_o[ray * 3 + 0], oy = rays_o[ray * 3 + 1],
                oz = rays_o[ray * 3 + 2];
    const float dx = rays_d[ray * 3 + 0], dy = rays_d[ray * 3 + 1],
                dz = rays_d[ray * 3 + 2];
    const float a0x = aabb[0], a0y = aabb[1], a0z = aabb[2];
    const float a1x = aabb[3], a1y = aabb[4], a1z = aabb[5];
    const float ex = a1x - a0x, ey = a1y - a0y, ez = a1z - a0z;
    const float step = sqrtf(ex * ex + ey * ey + ez * ez) / (float)N_SAMPLES;

    // ray/AABB entry t (mirrors reference: per-dim min over planes, max over dims)
    float ddx = (dx == 0.f) ? dx + 1e-9f : dx;
    float ddy = (dy == 0.f) ? dy + 1e-9f : dy;
    float ddz = (dz == 0.f) ? dz + 1e-9f : dz;
    float ix = fminf((a0x - ox) / ddx, (a1x - ox) / ddx);
    float iy = fminf((a0y - oy) / ddy, (a1y - oy) / ddy);
    float iz = fminf((a0z - oz) / ddz, (a1z - oz) / ddz);
    float t_min = fmaxf(fmaxf(ix, iy), iz);
    t_min = fminf(fmaxf(t_min, 0.f), 100000.f);

    // per-thread weight slices (coalesced, L1-resident)
    const float wf1_0 = fw1[0 * FEAT + f];
    const float wf1_1 = fw1[1 * FEAT + f];
    const float wf1_2 = fw1[2 * FEAT + f];
    const float wfb1 = fb1[f];
    const float wfb2 = fb2[f];
    const float wsw = sw[f];
    const float sb0 = sb[0];
    // direction contribution to rgb-hidden for this feature (constant per ray)
    const float rh_dir = dx * rw1[64 * FEAT + f] + dy * rw1[65 * FEAT + f] +
                         dz * rw1[66 * FEAT + f] + rb1[f];
    const float wr2_0 = rw2[f * 3 + 0];
    const float wr2_1 = rw2[f * 3 + 1];
    const float wr2_2 = rw2[f * 3 + 2];
    const float rb2_0 = rb2[0], rb2_1 = rb2[1], rb2_2 = rb2[2];

    float trans = 1.f;
    float acc0 = 0.f, acc1 = 0.f, acc2 = 0.f;

    for (int s = 0; s < N_SAMPLES; ++s) {
        float t = t_min + (float)s * step;
        float px = ox + dx * t, py = oy + dy * t, pz = oz + dz * t;
        bool inside = (px >= a0x) & (px <= a1x) & (py >= a0y) & (py <= a1y) &
                      (pz >= a0z) & (pz <= a1z);
        bool m = false;
        float scx = 0.f, scy = 0.f, scz = 0.f;
        if (inside) {  // wave-uniform branch: whole wave shares the sample
            scx = (px - a0x) / ex * 2.f - 1.f;
            scy = (py - a0y) / ey * 2.f - 1.f;
            scz = (pz - a0z) / ez * 2.f - 1.f;
            float occ = trilinear(grid, scx, scy, scz);
            m = occ > 0.01f;  // min(THRESHOLD=0.01, MEAN=1.0)
        }
        if (m) {
            // h = relu(sc @ fw1 + fb1)
            float h = fmaxf(scx * wf1_0 + scy * wf1_1 + scz * wf1_2 + wfb1, 0.f);
            s_h[f] = h;
            __syncthreads();
            // feat = h @ fw2 + fb2
            float fe = wfb2;
#pragma unroll
            for (int j = 0; j < FEAT; ++j) fe += s_h[j] * fw2[j * FEAT + f];
            s_feat[f] = fe;
            // sigma = feat @ sw + sb  (64-lane butterfly reduce)
            float p = fe * wsw;
#pragma unroll
            for (int off = 32; off > 0; off >>= 1) p += __shfl_xor(p, off);
            float sigma = p + sb0;
            __syncthreads();

            bool m2 = trans > 1e-4f;
            float e = expf(-sigma * step);
            float alpha = 1.f - e;
            float weight = trans * alpha;
            if (m2) {
                // rh = relu([feat, dir] @ rw1 + rb1)
                float rh = rh_dir;
#pragma unroll
                for (int j = 0; j < FEAT; ++j) rh += s_feat[j] * rw1[j * FEAT + f];
                rh = fmaxf(rh, 0.f);
                float q0 = rh * wr2_0, q1 = rh * wr2_1, q2 = rh * wr2_2;
#pragma unroll
                for (int off = 32; off > 0; off >>= 1) {
                    q0 += __shfl_xor(q0, off);
                    q1 += __shfl_xor(q1, off);
                    q2 += __shfl_xor(q2, off);
                }
                float r0 = 1.f / (1.f + expf(-(q0 + rb2_0)));
                float r1 = 1.f / (1.f + expf(-(q1 + rb2_1)));
                float r2 = 1.f / (1.f + expf(-(q2 + rb2_2)));
                acc0 += weight * r0;
                acc1 += weight * r1;
                acc2 += weight * r2;
            }
            trans *= e;
        }
    }
    if (f == 0) {
        out[ray * 3 + 0] = acc0;
        out[ray * 3 + 1] = acc1;
        out[ray * 3 + 2] = acc2;
    }
}

extern "C" void kernel_launch(void* const* d_in, const int* in_sizes, int n_in,
                              void* d_out, int out_size, void* d_ws,
                              size_t ws_size, hipStream_t stream) {
    const float* rays_o = (const float*)d_in[0];
    const float* rays_d = (const float*)d_in[1];
    const float* grid = (const float*)d_in[2];
    const float* aabb = (const float*)d_in[3];
    const float* fw1 = (const float*)d_in[4];
    const float* fb1 = (const float*)d_in[5];
    const float* fw2 = (const float*)d_in[6];
    const float* fb2 = (const float*)d_in[7];
    const float* sw = (const float*)d_in[8];
    const float* sb = (const float*)d_in[9];
    const float* rw1 = (const float*)d_in[10];
    const float* rb1 = (const float*)d_in[11];
    const float* rw2 = (const float*)d_in[12];
    const float* rb2 = (const float*)d_in[13];
    float* out = (float*)d_out;
    const int n_rays = in_sizes[0] / 3;

    nerf_kernel<<<n_rays, 64, 0, stream>>>(rays_o, rays_d, grid, aabb, fw1,
                                           fb1, fw2, fb2, sw, sb, rw1, rb1,
                                           rw2, rb2, out);
}

// Round 3
// 150.978 us; speedup vs baseline: 13.3748x; 13.3748x over previous
//
#include <hip/hip_runtime.h>
#include <math.h>

#define NS 200
#define FEAT 64
#define GRIDN 128

__device__ __forceinline__ float rl(float v, int l) {
    return __uint_as_float(
        __builtin_amdgcn_readlane(__float_as_uint(v), (unsigned)l));
}

__device__ __forceinline__ float trilinear(const float* __restrict__ g,
                                           float x, float y, float z) {
    const float W = 128.f, H = 128.f, D = 128.f;
    float gx = ((x + 1.f) * W - 1.f) * 0.5f;
    float gy = ((y + 1.f) * H - 1.f) * 0.5f;
    float gz = ((z + 1.f) * D - 1.f) * 0.5f;
    float x0 = floorf(gx), y0 = floorf(gy), z0 = floorf(gz);
    float out = 0.f;
#pragma unroll
    for (int dz = 0; dz < 2; ++dz)
#pragma unroll
        for (int dy = 0; dy < 2; ++dy)
#pragma unroll
            for (int dx = 0; dx < 2; ++dx) {
                float xi = x0 + dx, yi = y0 + dy, zi = z0 + dz;
                float w = (1.f - fabsf(gx - xi)) * (1.f - fabsf(gy - yi)) *
                          (1.f - fabsf(gz - zi));
                bool valid = (xi >= 0.f) && (xi < W) && (yi >= 0.f) &&
                             (yi < H) && (zi >= 0.f) && (zi < D);
                int xc = (int)fminf(fmaxf(xi, 0.f), 127.f);
                int yc = (int)fminf(fmaxf(yi, 0.f), 127.f);
                int zc = (int)fminf(fmaxf(zi, 0.f), 127.f);
                float v = valid ? g[(zc * GRIDN + yc) * GRIDN + xc] : 0.f;
                out += w * v;
            }
    return out;
}

// ws usage: ONLY 65 floats. ws[0..63] = w2s = fw2@sw ; ws[64] = fb2@sw + sb
__global__ __launch_bounds__(128) void precomp(const float* __restrict__ fw2,
                                               const float* __restrict__ sw,
                                               const float* __restrict__ fb2,
                                               const float* __restrict__ sb,
                                               float* __restrict__ ws) {
    int tid = threadIdx.x;
    if (tid < FEAT) {
        float a = 0.f;
        for (int j = 0; j < FEAT; ++j) a += fw2[tid * FEAT + j] * sw[j];
        ws[tid] = a;
    } else if (tid == FEAT) {
        float a = sb[0];
        for (int j = 0; j < FEAT; ++j) a += fb2[j] * sw[j];
        ws[FEAT] = a;
    }
}

__global__ __launch_bounds__(256) void render(
    const float* __restrict__ ro, const float* __restrict__ rd,
    const float* __restrict__ gvol, const float* __restrict__ aabb,
    const float* __restrict__ fw1, const float* __restrict__ fb1,
    const float* __restrict__ fw2, const float* __restrict__ fb2,
    const float* __restrict__ rw1, const float* __restrict__ rb1,
    const float* __restrict__ rw2, const float* __restrict__ rb2,
    const float* __restrict__ ws, float* __restrict__ out) {
    __shared__ float s_w1[4 * FEAT];  // fw1 rows 0..2 then fb1
    __shared__ float s_w2s[FEAT];
    __shared__ float s_sig[NS];   // sigma, later effective weight
    __shared__ float s_la[256];   // scan buffer
    __shared__ float s_fw2[FEAT * FEAT];
    __shared__ float s_rw1[FEAT * FEAT];
    __shared__ float s_acc[4][3];
    __shared__ int s_flag;

    const int ray = blockIdx.x;
    const int tid = threadIdx.x;
    const int f = tid & 63, wv = tid >> 6;

    if (tid < 192) s_w1[tid] = fw1[tid];
    else s_w1[tid] = fb1[tid - 192];
    if (tid < FEAT) s_w2s[tid] = ws[tid];
    if (tid == 0) s_flag = 0;
    const float cbias = ws[FEAT];

    const float ox = ro[ray * 3 + 0], oy = ro[ray * 3 + 1],
                oz = ro[ray * 3 + 2];
    const float dx = rd[ray * 3 + 0], dy = rd[ray * 3 + 1],
                dz = rd[ray * 3 + 2];
    const float a0x = aabb[0], a0y = aabb[1], a0z = aabb[2];
    const float a1x = aabb[3], a1y = aabb[4], a1z = aabb[5];
    const float ex = a1x - a0x, ey = a1y - a0y, ez = a1z - a0z;
    const float step = sqrtf(ex * ex + ey * ey + ez * ez) / (float)NS;
    float ddx = (dx == 0.f) ? dx + 1e-9f : dx;
    float ddy = (dy == 0.f) ? dy + 1e-9f : dy;
    float ddz = (dz == 0.f) ? dz + 1e-9f : dz;
    float ixm = fminf((a0x - ox) / ddx, (a1x - ox) / ddx);
    float iym = fminf((a0y - oy) / ddy, (a1y - oy) / ddy);
    float izm = fminf((a0z - oz) / ddz, (a1z - oz) / ddz);
    float t_min = fmaxf(fmaxf(ixm, iym), izm);
    t_min = fminf(fmaxf(t_min, 0.f), 100000.f);

    __syncthreads();

    // ---- phase B: per-thread sample sigma (threads 0..199) ----
    float sig = 0.f;
    if (tid < NS) {
        float t = t_min + (float)tid * step;
        float px = ox + dx * t, py = oy + dy * t, pz = oz + dz * t;
        bool inside = (px >= a0x) & (px <= a1x) & (py >= a0y) & (py <= a1y) &
                      (pz >= a0z) & (pz <= a1z);
        if (inside) {
            float scx = (px - a0x) / ex * 2.f - 1.f;
            float scy = (py - a0y) / ey * 2.f - 1.f;
            float scz = (pz - a0z) / ez * 2.f - 1.f;
            if (trilinear(gvol, scx, scy, scz) > 0.01f) {
                float acc = cbias;
                for (int j = 0; j < FEAT; ++j) {
                    float h = scx * s_w1[j] + scy * s_w1[64 + j] +
                              scz * s_w1[128 + j] + s_w1[192 + j];
                    acc += fmaxf(h, 0.f) * s_w2s[j];
                }
                sig = acc;
            }
        }
    }

    // ---- phase C: block scan of log_a -> trans -> weights ----
    float la = (tid < NS) ? -sig * step : 0.f;
    s_la[tid] = la;
    __syncthreads();
    float run = la;
#pragma unroll
    for (int off = 1; off < 256; off <<= 1) {
        float add = (tid >= off) ? s_la[tid - off] : 0.f;
        __syncthreads();
        run += add;
        s_la[tid] = run;
        __syncthreads();
    }
    if (tid < NS) {
        float trans = expf(run - la);  // prefix before this sample
        float e = expf(la);            // exp(-sigma*step)
        float w = (trans > 1e-4f) ? trans * (1.f - e) : 0.f;
        s_sig[tid] = w;
        if (w != 0.f) s_flag = 1;
    }
    __syncthreads();
    if (!s_flag) {
        if (tid < 3) out[ray * 3 + tid] = 0.f;
        return;
    }

    // ---- phase E: rgb head for nonzero-weight samples ----
    for (int k = tid; k < FEAT * FEAT; k += 256) {
        s_fw2[k] = fw2[k];
        s_rw1[k] = rw1[k];  // rows 0..63 of rw1
    }
    const float fb2f = fb2[f];
    const float rh_dir = dx * rw1[64 * FEAT + f] + dy * rw1[65 * FEAT + f] +
                         dz * rw1[66 * FEAT + f] + rb1[f];
    const float w20 = rw2[f * 3 + 0], w21 = rw2[f * 3 + 1],
                w22 = rw2[f * 3 + 2];
    const float r20 = rb2[0], r21 = rb2[1], r22 = rb2[2];
    __syncthreads();

    float a0 = 0.f, a1 = 0.f, a2 = 0.f;
    for (int s = wv; s < NS; s += 4) {
        float w_s = s_sig[s];  // same address across wave -> uniform
        if (w_s != 0.f) {
            float t = t_min + (float)s * step;
            float px = ox + dx * t, py = oy + dy * t, pz = oz + dz * t;
            float scx = (px - a0x) / ex * 2.f - 1.f;
            float scy = (py - a0y) / ey * 2.f - 1.f;
            float scz = (pz - a0z) / ez * 2.f - 1.f;
            float h = fmaxf(scx * s_w1[f] + scy * s_w1[64 + f] +
                                scz * s_w1[128 + f] + s_w1[192 + f],
                            0.f);
            float fe = fb2f;
#pragma unroll
            for (int j = 0; j < FEAT; ++j)
                fe += rl(h, j) * s_fw2[j * FEAT + f];
            float rh = rh_dir;
#pragma unroll
            for (int j = 0; j < FEAT; ++j)
                rh += rl(fe, j) * s_rw1[j * FEAT + f];
            rh = fmaxf(rh, 0.f);
            float q0 = rh * w20, q1 = rh * w21, q2 = rh * w22;
#pragma unroll
            for (int off = 32; off > 0; off >>= 1) {
                q0 += __shfl_xor(q0, off);
                q1 += __shfl_xor(q1, off);
                q2 += __shfl_xor(q2, off);
            }
            a0 += w_s / (1.f + expf(-(q0 + r20)));
            a1 += w_s / (1.f + expf(-(q1 + r21)));
            a2 += w_s / (1.f + expf(-(q2 + r22)));
        }
    }
    if (f == 0) {
        s_acc[wv][0] = a0;
        s_acc[wv][1] = a1;
        s_acc[wv][2] = a2;
    }
    __syncthreads();
    if (tid == 0) {
        out[ray * 3 + 0] =
            s_acc[0][0] + s_acc[1][0] + s_acc[2][0] + s_acc[3][0];
        out[ray * 3 + 1] =
            s_acc[0][1] + s_acc[1][1] + s_acc[2][1] + s_acc[3][1];
        out[ray * 3 + 2] =
            s_acc[0][2] + s_acc[1][2] + s_acc[2][2] + s_acc[3][2];
    }
}

extern "C" void kernel_launch(void* const* d_in, const int* in_sizes, int n_in,
                              void* d_out, int out_size, void* d_ws,
                              size_t ws_size, hipStream_t stream) {
    const float* rays_o = (const float*)d_in[0];
    const float* rays_d = (const float*)d_in[1];
    const float* grid = (const float*)d_in[2];
    const float* aabb = (const float*)d_in[3];
    const float* fw1 = (const float*)d_in[4];
    const float* fb1 = (const float*)d_in[5];
    const float* fw2 = (const float*)d_in[6];
    const float* fb2 = (const float*)d_in[7];
    const float* sw = (const float*)d_in[8];
    const float* sb = (const float*)d_in[9];
    const float* rw1 = (const float*)d_in[10];
    const float* rb1 = (const float*)d_in[11];
    const float* rw2 = (const float*)d_in[12];
    const float* rb2 = (const float*)d_in[13];
    float* out = (float*)d_out;
    float* ws = (float*)d_ws;
    const int n_rays = in_sizes[0] / 3;

    precomp<<<1, 128, 0, stream>>>(fw2, sw, fb2, sb, ws);
    render<<<n_rays, 256, 0, stream>>>(rays_o, rays_d, grid, aabb, fw1, fb1,
                                       fw2, fb2, rw1, rb1, rw2, rb2, ws, out);
}